// Round 1
// baseline (110.514 us; speedup 1.0000x reference)
//
#include <hip/hip_runtime.h>
#include <hip/hip_bf16.h>

// Problem constants (from reference): B=16, T=512, D=512, L=4096 (derived from out_size)
#define BSZ 16
#define TT 512
#define DD 512
#define MM (BSZ * TT)          // 8192 rows for the GEMM
#define NB_COLBLK 8            // N=512 / BN=64

// ---------------- cumsum: one block per batch, inclusive scan of target[b,:] ----------------
__global__ __launch_bounds__(512) void cumsum_kernel(const int* __restrict__ target,
                                                     int* __restrict__ cs) {
    int b = blockIdx.x;
    __shared__ int s[TT];
    int t = threadIdx.x;
    s[t] = target[b * TT + t];
    __syncthreads();
    #pragma unroll
    for (int off = 1; off < TT; off <<= 1) {
        int v = (t >= off) ? s[t - off] : 0;
        __syncthreads();
        s[t] += v;
        __syncthreads();
    }
    cs[b * TT + t] = s[t];
}

// ---------------- length-regulate gather: out[b,l,:] = x[b, idx(l), :] or 0 ----------------
// grid: (B, L/ROWS); block 256 = 2 row-groups x 128 threads (one float4 per thread per row)
#define LR_ROWS 64
__global__ __launch_bounds__(256) void lr_kernel(const float* __restrict__ x,
                                                 const int* __restrict__ cs,
                                                 float* __restrict__ out, int L) {
    int b = blockIdx.x;
    __shared__ int scs[TT];
    for (int i = threadIdx.x; i < TT; i += 256) scs[i] = cs[b * TT + i];
    __syncthreads();
    int total = scs[TT - 1];
    int group = threadIdx.x >> 7;     // 0 or 1
    int lane  = threadIdx.x & 127;    // float4 index within a 512-float row
    int row0  = blockIdx.y * LR_ROWS;
    const float4* x4 = (const float4*)(x + (size_t)b * TT * DD);
    float4*       o4 = (float4*)(out + (size_t)b * L * DD);
    for (int r = row0 + group; r < row0 + LR_ROWS; r += 2) {
        int l = r;
        float4 v = make_float4(0.f, 0.f, 0.f, 0.f);
        if (l < total) {
            // idx = #{ i : cs[i] <= l }  (searchsorted side='right'), clipped to T-1
            int lo = 0, hi = TT;
            while (lo < hi) {               // uniform within each wave -> no divergence cost
                int mid = (lo + hi) >> 1;
                if (scs[mid] <= l) lo = mid + 1; else hi = mid;
            }
            int idx = lo < (TT - 1) ? lo : (TT - 1);
            v = x4[idx * (DD / 4) + lane];
        }
        o4[(size_t)l * (DD / 4) + lane] = v;
    }
}

// ---------------- fused GEMM1 + layer-2 partial dot ----------------
// h = relu(x @ W1 + b1) [8192,512]; per 64-col block: partial[bn][m] = sum_j h[m,j]*W2[j]
#define BMr 64
#define BNr 64
#define BKr 16
#define LDA_PAD 68
__global__ __launch_bounds__(256) void gemm1_kernel(const float* __restrict__ x,
                                                    const float* __restrict__ W1,
                                                    const float* __restrict__ b1,
                                                    const float* __restrict__ W2,
                                                    float* __restrict__ partial) {
    const int K = DD, N = DD;
    __shared__ float As[BKr][LDA_PAD];   // [k][m]
    __shared__ float Bs[BKr][LDA_PAD];   // [k][n]
    __shared__ float red[BMr][17];
    int tid = threadIdx.x;
    int bm = blockIdx.x, bn = blockIdx.y;
    int row0 = bm * BMr, col0 = bn * BNr;
    int tx = tid & 15, ty = tid >> 4;
    float acc[4][4] = {};
    for (int k0 = 0; k0 < K; k0 += BKr) {
        #pragma unroll
        for (int i = 0; i < 4; ++i) {
            int idx = tid + i * 256;      // 0..1023
            int r = idx >> 4;             // 0..63 (m)
            int c = idx & 15;             // 0..15 (k)
            As[c][r] = x[(size_t)(row0 + r) * K + k0 + c];
        }
        #pragma unroll
        for (int i = 0; i < 4; ++i) {
            int idx = tid + i * 256;
            int r = idx >> 6;             // 0..15 (k)
            int c = idx & 63;             // 0..63 (n)
            Bs[r][c] = W1[(size_t)(k0 + r) * N + col0 + c];
        }
        __syncthreads();
        #pragma unroll
        for (int kk = 0; kk < BKr; ++kk) {
            float a[4], bb[4];
            #pragma unroll
            for (int i = 0; i < 4; ++i) a[i] = As[kk][ty * 4 + i];
            #pragma unroll
            for (int j = 0; j < 4; ++j) bb[j] = Bs[kk][tx * 4 + j];
            #pragma unroll
            for (int i = 0; i < 4; ++i)
                #pragma unroll
                for (int j = 0; j < 4; ++j)
                    acc[i][j] += a[i] * bb[j];
        }
        __syncthreads();
    }
    // epilogue: relu + dot with W2 over this block's 64 columns
    float p[4];
    #pragma unroll
    for (int i = 0; i < 4; ++i) {
        float s = 0.f;
        #pragma unroll
        for (int j = 0; j < 4; ++j) {
            int col = col0 + tx * 4 + j;
            float h = acc[i][j] + b1[col];
            h = fmaxf(h, 0.f);
            s += h * W2[col];
        }
        p[i] = s;
    }
    #pragma unroll
    for (int i = 0; i < 4; ++i) red[ty * 4 + i][tx] = p[i];
    __syncthreads();
    if (tid < BMr) {
        float s = 0.f;
        #pragma unroll
        for (int t = 0; t < 16; ++t) s += red[tid][t];
        partial[(size_t)bn * MM + row0 + tid] = s;
    }
}

// ---------------- final dpo: relu(sum of 8 partials + b2) ----------------
__global__ __launch_bounds__(256) void dpo_kernel(const float* __restrict__ partial,
                                                  const float* __restrict__ b2,
                                                  float* __restrict__ dpo) {
    int m = blockIdx.x * 256 + threadIdx.x;
    float s = b2[0];
    #pragma unroll
    for (int nb = 0; nb < NB_COLBLK; ++nb) s += partial[(size_t)nb * MM + m];
    dpo[m] = fmaxf(s, 0.f);
}

extern "C" void kernel_launch(void* const* d_in, const int* in_sizes, int n_in,
                              void* d_out, int out_size, void* d_ws, size_t ws_size,
                              hipStream_t stream) {
    const float* x      = (const float*)d_in[0];
    const float* W1     = (const float*)d_in[1];
    const float* b1     = (const float*)d_in[2];
    const float* W2     = (const float*)d_in[3];
    const float* b2     = (const float*)d_in[4];
    const int*   target = (const int*)d_in[5];
    // d_in[6] = mel_max_length (device scalar); derive L from out_size instead:
    int L = (out_size - BSZ * TT) / (BSZ * DD);   // = 4096

    float* out_lr  = (float*)d_out;                       // [B, L, D]
    float* out_dpo = (float*)d_out + (size_t)BSZ * L * DD; // [B, T]

    float* partial = (float*)d_ws;                         // [8][8192] floats
    int*   cs      = (int*)((float*)d_ws + (size_t)NB_COLBLK * MM); // [B][T]

    cumsum_kernel<<<dim3(BSZ), dim3(TT), 0, stream>>>(target, cs);
    lr_kernel<<<dim3(BSZ, L / LR_ROWS), dim3(256), 0, stream>>>(x, cs, out_lr, L);
    gemm1_kernel<<<dim3(MM / BMr, NB_COLBLK), dim3(256), 0, stream>>>(x, W1, b1, W2, partial);
    dpo_kernel<<<dim3(MM / 256), dim3(256), 0, stream>>>(partial, b2, out_dpo);
}

// Round 3
// 70.430 us; speedup vs baseline: 1.5691x; 1.5691x over previous
//
#include <hip/hip_runtime.h>
#include <hip/hip_bf16.h>

#define BSZ 16
#define TT 512
#define DD 512
#define MM (BSZ * TT)          // 8192 rows for the GEMM
#define NCB 4                  // N=512 / BN=128 col-blocks
#define NPART (NCB * 2)        // partial slices: col-block x col-half

typedef __attribute__((ext_vector_type(8))) short bf16x8;
typedef __attribute__((ext_vector_type(4))) float f32x4;

// ---------------- cumsum: one block per batch, inclusive scan of target[b,:] ----------------
__global__ __launch_bounds__(512) void cumsum_kernel(const int* __restrict__ target,
                                                     int* __restrict__ cs) {
    int b = blockIdx.x;
    __shared__ int s[TT];
    int t = threadIdx.x;
    s[t] = target[b * TT + t];
    __syncthreads();
    #pragma unroll
    for (int off = 1; off < TT; off <<= 1) {
        int v = (t >= off) ? s[t - off] : 0;
        __syncthreads();
        s[t] += v;
        __syncthreads();
    }
    cs[b * TT + t] = s[t];
}

// ---------------- length-regulate gather ----------------
#define LR_ROWS 64
__global__ __launch_bounds__(256) void lr_kernel(const float* __restrict__ x,
                                                 const int* __restrict__ cs,
                                                 float* __restrict__ out, int L) {
    int b = blockIdx.x;
    __shared__ int scs[TT];
    for (int i = threadIdx.x; i < TT; i += 256) scs[i] = cs[b * TT + i];
    __syncthreads();
    int total = scs[TT - 1];
    int group = threadIdx.x >> 7;
    int lane  = threadIdx.x & 127;
    int row0  = blockIdx.y * LR_ROWS;
    const float4* x4 = (const float4*)(x + (size_t)b * TT * DD);
    float4*       o4 = (float4*)(out + (size_t)b * L * DD);
    for (int r = row0 + group; r < row0 + LR_ROWS; r += 2) {
        int l = r;
        float4 v = make_float4(0.f, 0.f, 0.f, 0.f);
        if (l < total) {
            int lo = 0, hi = TT;
            while (lo < hi) {
                int mid = (lo + hi) >> 1;
                if (scs[mid] <= l) lo = mid + 1; else hi = mid;
            }
            int idx = lo < (TT - 1) ? lo : (TT - 1);
            v = x4[idx * (DD / 4) + lane];
        }
        o4[(size_t)l * (DD / 4) + lane] = v;
    }
}

// ---------------- split-precision conversion: x -> xh + xl (bf16 each) ----------------
__global__ __launch_bounds__(256) void convert_x_kernel(const float* __restrict__ x,
                                                        ushort* __restrict__ xh,
                                                        ushort* __restrict__ xl) {
    int i = blockIdx.x * 256 + threadIdx.x;      // 1048576 threads, 4 floats each
    float4 v = ((const float4*)x)[i];
    float f[4] = {v.x, v.y, v.z, v.w};
    ushort hh[4], ll[4];
    #pragma unroll
    for (int j = 0; j < 4; ++j) {
        __hip_bfloat16 bh = __float2bfloat16(f[j]);
        float r = f[j] - __bfloat162float(bh);
        __hip_bfloat16 bl = __float2bfloat16(r);
        hh[j] = *(ushort*)&bh; ll[j] = *(ushort*)&bl;
    }
    ((ushort4*)xh)[i] = make_ushort4(hh[0], hh[1], hh[2], hh[3]);
    ((ushort4*)xl)[i] = make_ushort4(ll[0], ll[1], ll[2], ll[3]);
}

// ---------------- W1 -> transposed split bf16: wth[n][k], wtl[n][k] ----------------
__global__ __launch_bounds__(256) void convert_w_kernel(const float* __restrict__ W1,
                                                        ushort* __restrict__ wth,
                                                        ushort* __restrict__ wtl) {
    int t = blockIdx.x * 256 + threadIdx.x;      // 65536 threads
    int n  = t & (DD - 1);
    int kq = t >> 9;                             // 0..127, covers k = kq*4..+3
    ushort hh[4], ll[4];
    #pragma unroll
    for (int i = 0; i < 4; ++i) {
        float f = W1[(size_t)(kq * 4 + i) * DD + n];
        __hip_bfloat16 bh = __float2bfloat16(f);
        float r = f - __bfloat162float(bh);
        __hip_bfloat16 bl = __float2bfloat16(r);
        hh[i] = *(ushort*)&bh; ll[i] = *(ushort*)&bl;
    }
    ((ushort4*)wth)[(size_t)n * (DD / 4) + kq] = make_ushort4(hh[0], hh[1], hh[2], hh[3]);
    ((ushort4*)wtl)[(size_t)n * (DD / 4) + kq] = make_ushort4(ll[0], ll[1], ll[2], ll[3]);
}

// ---------------- bf16x3 MFMA GEMM + fused layer-2 partial dot ----------------
// Tile 128x128, BK=32. LDS row layout: [row][slot0..7] where slots 0-3 = hi bf16
// (k0..k0+31), slots 4-7 = lo bf16. 128 B rows -> XOR swizzle slot ^= (row&7).
// global_load_lds writes linearly; the global SOURCE address is pre-inverse-swizzled.
#define BM 128
#define BN 128
#define BK 32
__global__ __launch_bounds__(256) void gemm_kernel(const ushort* __restrict__ xh,
                                                   const ushort* __restrict__ xl,
                                                   const ushort* __restrict__ wth,
                                                   const ushort* __restrict__ wtl,
                                                   const float* __restrict__ b1,
                                                   const float* __restrict__ W2,
                                                   float* __restrict__ partial) {
    __shared__ ushort lds[2][2][128 * 64];   // [buf][A/B][row*64 + slot*8 + e] = 64 KB
    const int t = threadIdx.x;
    const int lane = t & 63, wave = t >> 6;
    const int row0 = blockIdx.x * BM;
    const int col0 = blockIdx.y * BN;
    const int rq = t >> 3;                   // row within a 32-row issue chunk
    const int ls = (t & 7) ^ (rq & 7);       // logical slot this lane must FETCH
    const int sco = (ls & 3) * 8;            // k-subcolumn within tile

    auto stage = [&](int buf, int kt) {
        const int k0 = kt * BK;
        const ushort* srcA = (ls < 4) ? xh : xl;
        const ushort* srcB = (ls < 4) ? wth : wtl;
        #pragma unroll
        for (int q = 0; q < 4; ++q) {
            int row = q * 32 + rq;
            const ushort* ga = srcA + (size_t)(row0 + row) * DD + k0 + sco;
            auto la = (__attribute__((address_space(3))) unsigned int*)
                      ((char*)&lds[buf][0][0] + q * 4096 + wave * 1024);
            __builtin_amdgcn_global_load_lds(
                (const __attribute__((address_space(1))) unsigned int*)ga, la, 16, 0, 0);
        }
        #pragma unroll
        for (int q = 0; q < 4; ++q) {
            int row = q * 32 + rq;
            const ushort* gb = srcB + (size_t)(col0 + row) * DD + k0 + sco;
            auto lb = (__attribute__((address_space(3))) unsigned int*)
                      ((char*)&lds[buf][1][0] + q * 4096 + wave * 1024);
            __builtin_amdgcn_global_load_lds(
                (const __attribute__((address_space(1))) unsigned int*)gb, lb, 16, 0, 0);
        }
    };

    const int wm = (wave >> 1) * 64;   // wave's row offset within tile
    const int wn = (wave & 1) * 64;    // wave's col offset within tile
    const int l15 = lane & 15, l4 = lane >> 4;
    f32x4 acc[4][4] = {};

    stage(0, 0);
    __syncthreads();
    int cur = 0;
    #pragma unroll 1
    for (int kt = 0; kt < DD / BK; ++kt) {
        if (kt + 1 < DD / BK) stage(cur ^ 1, kt + 1);
        const ushort* At = &lds[cur][0][0];
        const ushort* Bt = &lds[cur][1][0];
        bf16x8 ah[4], al[4], bh[4], bl[4];
        #pragma unroll
        for (int i = 0; i < 4; ++i) {
            int r = wm + i * 16 + l15;
            int s0 = l4 ^ (r & 7);
            int s1 = (4 + l4) ^ (r & 7);
            ah[i] = *(const bf16x8*)&At[r * 64 + s0 * 8];
            al[i] = *(const bf16x8*)&At[r * 64 + s1 * 8];
        }
        #pragma unroll
        for (int j = 0; j < 4; ++j) {
            int r = wn + j * 16 + l15;
            int s0 = l4 ^ (r & 7);
            int s1 = (4 + l4) ^ (r & 7);
            bh[j] = *(const bf16x8*)&Bt[r * 64 + s0 * 8];
            bl[j] = *(const bf16x8*)&Bt[r * 64 + s1 * 8];
        }
        #pragma unroll
        for (int i = 0; i < 4; ++i)
            #pragma unroll
            for (int j = 0; j < 4; ++j) {
                acc[i][j] = __builtin_amdgcn_mfma_f32_16x16x32_bf16(ah[i], bh[j], acc[i][j], 0, 0, 0);
                acc[i][j] = __builtin_amdgcn_mfma_f32_16x16x32_bf16(ah[i], bl[j], acc[i][j], 0, 0, 0);
                acc[i][j] = __builtin_amdgcn_mfma_f32_16x16x32_bf16(al[i], bh[j], acc[i][j], 0, 0, 0);
            }
        __syncthreads();
        cur ^= 1;
    }

    // epilogue: relu(acc + b1) dot W2 over this block's 128 cols.
    // C/D layout (16x16): col = lane&15, row = (lane>>4)*4 + reg [m89]
    // partial slice = col-block * 2 + col-half (waves with wm equal, wn different
    // cover DIFFERENT column halves of the same rows -> must not share a slot!)
    const int pslice = blockIdx.y * 2 + (wn >> 6);
    #pragma unroll
    for (int i = 0; i < 4; ++i) {
        #pragma unroll
        for (int r = 0; r < 4; ++r) {
            float s = 0.f;
            #pragma unroll
            for (int j = 0; j < 4; ++j) {
                int cg = col0 + wn + j * 16 + l15;
                float h = acc[i][j][r] + b1[cg];
                h = fmaxf(h, 0.f);
                s += h * W2[cg];
            }
            s += __shfl_xor(s, 1);
            s += __shfl_xor(s, 2);
            s += __shfl_xor(s, 4);
            s += __shfl_xor(s, 8);
            if (l15 == 0) {
                int rg = row0 + wm + i * 16 + l4 * 4 + r;
                partial[(size_t)pslice * MM + rg] = s;
            }
        }
    }
}

// ---------------- final dpo: relu(sum of 8 partials + b2) ----------------
__global__ __launch_bounds__(256) void dpo_kernel(const float* __restrict__ partial,
                                                  const float* __restrict__ b2,
                                                  float* __restrict__ dpo) {
    int m = blockIdx.x * 256 + threadIdx.x;
    float s = b2[0];
    #pragma unroll
    for (int nb = 0; nb < NPART; ++nb) s += partial[(size_t)nb * MM + m];
    dpo[m] = fmaxf(s, 0.f);
}

extern "C" void kernel_launch(void* const* d_in, const int* in_sizes, int n_in,
                              void* d_out, int out_size, void* d_ws, size_t ws_size,
                              hipStream_t stream) {
    const float* x      = (const float*)d_in[0];
    const float* W1     = (const float*)d_in[1];
    const float* b1     = (const float*)d_in[2];
    const float* W2     = (const float*)d_in[3];
    const float* b2     = (const float*)d_in[4];
    const int*   target = (const int*)d_in[5];
    int L = (out_size - BSZ * TT) / (BSZ * DD);   // = 4096

    float* out_lr  = (float*)d_out;                        // [B, L, D]
    float* out_dpo = (float*)d_out + (size_t)BSZ * L * DD; // [B, T]

    // ws layout
    ushort* xh      = (ushort*)d_ws;                       // 8 MiB
    ushort* xl      = xh + (size_t)MM * DD;                // 8 MiB
    ushort* wth     = xl + (size_t)MM * DD;                // 512 KiB
    ushort* wtl     = wth + (size_t)DD * DD;               // 512 KiB
    float*  partial = (float*)(wtl + (size_t)DD * DD);     // 8*8192 floats
    int*    cs      = (int*)(partial + (size_t)NPART * MM); // 16*512 ints

    convert_x_kernel<<<dim3(MM * DD / 4 / 256), dim3(256), 0, stream>>>(x, xh, xl);
    convert_w_kernel<<<dim3(DD * DD / 4 / 256), dim3(256), 0, stream>>>(W1, wth, wtl);
    cumsum_kernel<<<dim3(BSZ), dim3(TT), 0, stream>>>(target, cs);
    gemm_kernel<<<dim3(MM / BM, NCB), dim3(256), 0, stream>>>(xh, xl, wth, wtl, b1, W2, partial);
    lr_kernel<<<dim3(BSZ, L / LR_ROWS), dim3(256), 0, stream>>>(x, cs, out_lr, L);
    dpo_kernel<<<dim3(MM / 256), dim3(256), 0, stream>>>(partial, b2, out_dpo);
}